// Round 1
// baseline (299.603 us; speedup 1.0000x reference)
//
#include <hip/hip_runtime.h>
#include <hip/hip_bf16.h>

#define EPS 1e-7f

typedef __attribute__((ext_vector_type(8))) short short8;
typedef __attribute__((ext_vector_type(4))) float f32x4;

__device__ __forceinline__ short f2bf(float x) {
    __hip_bfloat16 h = __float2bfloat16(x);
    short r; __builtin_memcpy(&r, &h, 2); return r;
}

// ---------------- prep: w_norm + normalized bf16 W in [tap][n][k] layout + p^2 ----------------
__global__ void prep_kernel(const float* __restrict__ w, const float* __restrict__ p,
                            short* __restrict__ Wn, float* __restrict__ p2) {
    const int t = blockIdx.x;   // tap 0..8
    const int n = threadIdx.x;  // filter 0..127
    float ssq = 0.f;
    for (int k = 0; k < 576; ++k) {
        float v = w[k * 128 + n];
        ssq = fmaf(v, v, ssq);
    }
    const float inv = 1.0f / sqrtf(fmaxf(ssq, EPS));
    short* dst = Wn + t * 8192 + n * 64;
    const float* src = w + t * 64 * 128 + n;
    for (int k2 = 0; k2 < 64; ++k2) {
        dst[k2] = f2bf(src[k2 * 128] * inv);
    }
    if (t == 0) p2[n] = p[n] * p[n];
}

// ---------------- main: implicit-GEMM 3x3 cosine conv ----------------
// tile: 16x16 pixels x 128 filters, 8 waves (4m x 2n), each wave 64x64
__global__ __launch_bounds__(512, 4)
void sharp_main(const float* __restrict__ img, const short* __restrict__ Wn,
                const float* __restrict__ bias, const float* __restrict__ p2g,
                const float* __restrict__ qp, float* __restrict__ out) {
    __shared__ __align__(16) unsigned char lds_img[41472];   // 324 pix * 64ch * 2B, swizzled
    __shared__ __align__(16) unsigned char lds_w[2][16384];  // per-tap [n=128][k=64] bf16, swizzled
    __shared__ float sArr[324];
    __shared__ float invxn[256];

    const int tid  = threadIdx.x;
    const int lane = tid & 63;
    const int wv   = tid >> 6;   // 0..7
    const int wm   = wv >> 1;    // 0..3 (m quadrant)
    const int wn   = wv & 1;     // 0..1 (n half)
    const int tx = blockIdx.x, ty = blockIdx.y, bz = blockIdx.z;
    const int y0 = ty * 16, x0 = tx * 16;

    const int mxl = lane & 15;   // A row / C col within fragment
    const int kq  = lane >> 4;   // k-quarter

    if (tid < 324) sArr[tid] = 0.f;
    __syncthreads();

    // ---- stage image tile (18x18 halo) f32 -> bf16 LDS, fused sum-of-squares ----
    {
        const long ibase = (long)bz * (112 * 112 * 64);
        for (int q = tid; q < 2592; q += 512) {   // 324 pixels * 8 chunks of 8ch
            const int pp = q >> 3, c8 = q & 7;
            const int py = pp / 18, px = pp % 18;
            const int gy = y0 - 1 + py, gx = x0 - 1 + px;
            short8 h = {0, 0, 0, 0, 0, 0, 0, 0};
            if ((unsigned)gy < 112u && (unsigned)gx < 112u) {
                const float* sp = img + ibase + ((gy * 112 + gx) << 6) + (c8 << 3);
                const float4 v0 = *reinterpret_cast<const float4*>(sp);
                const float4 v1 = *reinterpret_cast<const float4*>(sp + 4);
                float ss = v0.x * v0.x + v0.y * v0.y + v0.z * v0.z + v0.w * v0.w
                         + v1.x * v1.x + v1.y * v1.y + v1.z * v1.z + v1.w * v1.w;
                h[0] = f2bf(v0.x); h[1] = f2bf(v0.y); h[2] = f2bf(v0.z); h[3] = f2bf(v0.w);
                h[4] = f2bf(v1.x); h[5] = f2bf(v1.y); h[6] = f2bf(v1.z); h[7] = f2bf(v1.w);
                atomicAdd(&sArr[pp], ss);
            }
            const int addr = (pp << 7) + (((c8 << 4)) ^ ((pp & 7) << 4));
            *reinterpret_cast<short8*>(lds_img + addr) = h;
        }
    }

    // ---- stage W tap0, prefetch tap1 ----
    const uint4* wg = reinterpret_cast<const uint4*>(Wn);  // 1024 uint4 per tap
    const int wi0 = tid * 2, wi1 = tid * 2 + 1;
    const int wa0 = (tid * 32) ^ ((((tid * 32) >> 7) & 7) << 4);
    const int wa1 = (tid * 32 + 16) ^ ((((tid * 32) >> 7) & 7) << 4);
    uint4 r0 = wg[wi0], r1 = wg[wi1];
    *reinterpret_cast<uint4*>(lds_w[0] + wa0) = r0;
    *reinterpret_cast<uint4*>(lds_w[0] + wa1) = r1;
    r0 = wg[1024 + wi0]; r1 = wg[1024 + wi1];   // prefetch tap1 into regs

    __syncthreads();

    // ---- per-pixel inverse norm from 3x3 box of channel sumsq ----
    if (tid < 256) {
        const int my = tid >> 4, mx = tid & 15;
        float s9 = 0.f;
#pragma unroll
        for (int dy = 0; dy < 3; ++dy)
#pragma unroll
            for (int dx = 0; dx < 3; ++dx)
                s9 += sArr[(my + dy) * 18 + (mx + dx)];
        const float qv = qp[0];
        invxn[tid] = 1.0f / (sqrtf(fmaxf(s9, EPS)) + qv * qv);
    }
    __syncthreads();

    // ---- main MFMA loop: 9 taps x 2 k-steps ----
    f32x4 acc[4][4];
#pragma unroll
    for (int mi = 0; mi < 4; ++mi)
#pragma unroll
        for (int ni = 0; ni < 4; ++ni)
            acc[mi][ni] = (f32x4){0.f, 0.f, 0.f, 0.f};

#pragma unroll
    for (int t = 0; t < 9; ++t) {
        const int dy = t / 3, dx = t % 3;
        if (t < 8) {
            // write prefetched tap t+1 into the other buffer (safe: last read of it was tap t-1)
            *reinterpret_cast<uint4*>(lds_w[(t + 1) & 1] + wa0) = r0;
            *reinterpret_cast<uint4*>(lds_w[(t + 1) & 1] + wa1) = r1;
            if (t < 7) { r0 = wg[(t + 2) * 1024 + wi0]; r1 = wg[(t + 2) * 1024 + wi1]; }
        }
#pragma unroll
        for (int ks = 0; ks < 2; ++ks) {
            short8 af[4], bfr[4];
#pragma unroll
            for (int mi = 0; mi < 4; ++mi) {
                const int pp = (wm * 4 + mi + dy) * 18 + mxl + dx;
                const int addr = (pp << 7) + ((ks * 64 + kq * 16) ^ ((pp & 7) << 4));
                af[mi] = *reinterpret_cast<const short8*>(lds_img + addr);
            }
#pragma unroll
            for (int ni = 0; ni < 4; ++ni) {
                const int nn = wn * 64 + ni * 16 + mxl;
                const int addr = (nn << 7) + ((ks * 64 + kq * 16) ^ ((nn & 7) << 4));
                bfr[ni] = *reinterpret_cast<const short8*>(lds_w[t & 1] + addr);
            }
#pragma unroll
            for (int mi = 0; mi < 4; ++mi)
#pragma unroll
                for (int ni = 0; ni < 4; ++ni)
                    acc[mi][ni] = __builtin_amdgcn_mfma_f32_16x16x32_bf16(
                        af[mi], bfr[ni], acc[mi][ni], 0, 0, 0);
        }
        __syncthreads();
    }

    // ---- epilogue: cosine, sharpen, bias, store ----
    float p2v[4], bv[4];
#pragma unroll
    for (int ni = 0; ni < 4; ++ni) {
        const int f = wn * 64 + ni * 16 + mxl;
        p2v[ni] = p2g[f];
        bv[ni] = bias[f];
    }
    const long obase = (long)bz * 112 * 112 * 128;
#pragma unroll
    for (int mi = 0; mi < 4; ++mi) {
        const int my = wm * 4 + mi;
        const int gy = y0 + my;
#pragma unroll
        for (int j = 0; j < 4; ++j) {
            const int mx = kq * 4 + j;
            const float inv = invxn[my * 16 + mx];
            const int gx = x0 + mx;
            float* op = out + obase + ((long)(gy * 112 + gx) << 7);
#pragma unroll
            for (int ni = 0; ni < 4; ++ni) {
                const float cosv = acc[mi][ni][j] * inv;
                const float av = fabsf(cosv) + EPS;
                const float r = powf(av, p2v[ni]);
                const float val = (cosv == 0.f) ? bv[ni] : (copysignf(r, cosv) + bv[ni]);
                op[wn * 64 + ni * 16 + mxl] = val;
            }
        }
    }
}

extern "C" void kernel_launch(void* const* d_in, const int* in_sizes, int n_in,
                              void* d_out, int out_size, void* d_ws, size_t ws_size,
                              hipStream_t stream) {
    const float* img = (const float*)d_in[0];
    const float* w   = (const float*)d_in[1];
    const float* b   = (const float*)d_in[2];
    const float* p   = (const float*)d_in[3];
    const float* q   = (const float*)d_in[4];
    float* out = (float*)d_out;

    short* Wn = (short*)d_ws;                          // 9*128*64 bf16 = 147456 B
    float* p2 = (float*)((char*)d_ws + 9 * 8192 * 2);  // 128 f32

    prep_kernel<<<9, 128, 0, stream>>>(w, p, Wn, p2);
    sharp_main<<<dim3(7, 7, 16), 512, 0, stream>>>(img, Wn, b, p2, q, out);
}

// Round 3
// 251.292 us; speedup vs baseline: 1.1922x; 1.1922x over previous
//
#include <hip/hip_runtime.h>
#include <hip/hip_bf16.h>

#define EPS 1e-7f

typedef __attribute__((ext_vector_type(8))) short short8;
typedef __attribute__((ext_vector_type(4))) float f32x4;

__device__ __forceinline__ short f2bf(float x) {
    __hip_bfloat16 h = __float2bfloat16(x);
    short r; __builtin_memcpy(&r, &h, 2); return r;
}

__device__ __forceinline__ float fast_log2(float x) {
    float r; asm("v_log_f32 %0, %1" : "=v"(r) : "v"(x)); return r;
}
__device__ __forceinline__ float fast_exp2(float x) {
    float r; asm("v_exp_f32 %0, %1" : "=v"(r) : "v"(x)); return r;
}

// ---------------- prep: w_norm + normalized bf16 W in fragment-contiguous layout + p^2 ----
// Layout: Wn2[t][ks][g][mxl][kq][e]  (t=tap, ks=k-step/32, g=n/16, mxl=n%16, kq=(k%32)/8, e=k%8)
// so a wave's B-fragment load (lane = kq*16+mxl) for fixed (t,ks,g) is 64 consecutive 16B chunks.
__global__ void prep_kernel(const float* __restrict__ w, const float* __restrict__ p,
                            short* __restrict__ Wn2, float* __restrict__ p2) {
    __shared__ float pn[4][128];
    __shared__ float sInv[128];
    const int t = blockIdx.x;        // tap 0..8
    const int tid = threadIdx.x;     // 0..511
    const int n = tid & 127, part = tid >> 7;
    float ssq = 0.f;
    const int k0 = part * 144;
    for (int k = k0; k < k0 + 144; ++k) {
        float v = w[k * 128 + n];
        ssq = fmaf(v, v, ssq);
    }
    pn[part][n] = ssq;
    __syncthreads();
    if (tid < 128) {
        float s = pn[0][tid] + pn[1][tid] + pn[2][tid] + pn[3][tid];
        sInv[tid] = 1.0f / sqrtf(fmaxf(s, EPS));
        if (t == 0) p2[tid] = p[tid] * p[tid];
    }
    __syncthreads();
    if (tid < 256) {
        const int mxl = tid & 15, g = (tid >> 4) & 7, ks = tid >> 7;
        const int nn = g * 16 + mxl;
        const float inv = sInv[nn];
        short* dst = Wn2 + (((t * 2 + ks) * 8 + g) * 16 + mxl) * 32;
        const float* src = w + (t * 64 + ks * 32) * 128 + nn;
#pragma unroll
        for (int j = 0; j < 32; ++j) dst[j] = f2bf(src[j * 128] * inv);
    }
}

// ---------------- main: implicit-GEMM 3x3 cosine conv, barrier-free MFMA loop ----------------
// tile: 16x16 pixels x 128 filters, 8 waves (4m x 2n), each wave 64x64
__global__ __launch_bounds__(512, 4)
void sharp_main(const float* __restrict__ img, const short* __restrict__ Wn,
                const float* __restrict__ bias, const float* __restrict__ p2g,
                const float* __restrict__ qp, float* __restrict__ out) {
    __shared__ __align__(16) unsigned char lds_img[41472];   // 324 pix * 64ch * 2B, swizzled
    __shared__ float sArr[324];
    __shared__ float invxn[256];

    const int tid  = threadIdx.x;
    const int lane = tid & 63;
    const int wv   = tid >> 6;   // 0..7
    const int wm   = wv >> 1;    // 0..3 (m quadrant)
    const int wn   = wv & 1;     // 0..1 (n half)
    const int tx = blockIdx.x, ty = blockIdx.y, bz = blockIdx.z;
    const int y0 = ty * 16, x0 = tx * 16;

    const int mxl = lane & 15;   // A row / C col within fragment
    const int kq  = lane >> 4;   // k-quarter

    if (tid < 324) sArr[tid] = 0.f;
    __syncthreads();

    // ---- stage image tile (18x18 halo) f32 -> bf16 LDS, fused sum-of-squares ----
    {
        const long ibase = (long)bz * (112 * 112 * 64);
        for (int q = tid; q < 2592; q += 512) {   // 324 pixels * 8 chunks of 8ch
            const int pp = q >> 3, c8 = q & 7;
            const int py = pp / 18, px = pp % 18;
            const int gy = y0 - 1 + py, gx = x0 - 1 + px;
            short8 h = {0, 0, 0, 0, 0, 0, 0, 0};
            if ((unsigned)gy < 112u && (unsigned)gx < 112u) {
                const float* sp = img + ibase + ((gy * 112 + gx) << 6) + (c8 << 3);
                const float4 v0 = *reinterpret_cast<const float4*>(sp);
                const float4 v1 = *reinterpret_cast<const float4*>(sp + 4);
                float ss = v0.x * v0.x + v0.y * v0.y + v0.z * v0.z + v0.w * v0.w
                         + v1.x * v1.x + v1.y * v1.y + v1.z * v1.z + v1.w * v1.w;
                h[0] = f2bf(v0.x); h[1] = f2bf(v0.y); h[2] = f2bf(v0.z); h[3] = f2bf(v0.w);
                h[4] = f2bf(v1.x); h[5] = f2bf(v1.y); h[6] = f2bf(v1.z); h[7] = f2bf(v1.w);
                atomicAdd(&sArr[pp], ss);
            }
            const int addr = (pp << 7) + (((c8 << 4)) ^ ((pp & 7) << 4));
            *reinterpret_cast<short8*>(lds_img + addr) = h;
        }
    }
    __syncthreads();

    // ---- per-pixel inverse norm from 3x3 box of channel sumsq ----
    if (tid < 256) {
        const int my = tid >> 4, mx = tid & 15;
        float s9 = 0.f;
#pragma unroll
        for (int dy = 0; dy < 3; ++dy)
#pragma unroll
            for (int dx = 0; dx < 3; ++dx)
                s9 += sArr[(my + dy) * 18 + (mx + dx)];
        const float qv = qp[0];
        invxn[tid] = 1.0f / (sqrtf(fmaxf(s9, EPS)) + qv * qv);
    }
    __syncthreads();

    // ---- main MFMA loop: 9 taps x 2 k-steps, NO barriers (B direct from global, L2-hot) ----
    f32x4 acc[4][4];
#pragma unroll
    for (int mi = 0; mi < 4; ++mi)
#pragma unroll
        for (int ni = 0; ni < 4; ++ni)
            acc[mi][ni] = (f32x4){0.f, 0.f, 0.f, 0.f};

#pragma unroll
    for (int t = 0; t < 9; ++t) {
        const int dy = t / 3, dx = t % 3;
#pragma unroll
        for (int ks = 0; ks < 2; ++ks) {
            short8 af[4], bfr[4];
#pragma unroll
            for (int ni = 0; ni < 4; ++ni) {
                const int off = ((((t * 2 + ks) * 8 + wn * 4 + ni) * 16 + mxl) * 32) + kq * 8;
                bfr[ni] = *reinterpret_cast<const short8*>(Wn + off);
            }
#pragma unroll
            for (int mi = 0; mi < 4; ++mi) {
                const int pp = (wm * 4 + mi + dy) * 18 + mxl + dx;
                const int addr = (pp << 7) + ((ks * 64 + kq * 16) ^ ((pp & 7) << 4));
                af[mi] = *reinterpret_cast<const short8*>(lds_img + addr);
            }
#pragma unroll
            for (int mi = 0; mi < 4; ++mi)
#pragma unroll
                for (int ni = 0; ni < 4; ++ni)
                    acc[mi][ni] = __builtin_amdgcn_mfma_f32_16x16x32_bf16(
                        af[mi], bfr[ni], acc[mi][ni], 0, 0, 0);
        }
    }

    // ---- epilogue: cosine, sharpen (hw exp2/log2), bias, store ----
    float p2v[4], bv[4];
#pragma unroll
    for (int ni = 0; ni < 4; ++ni) {
        const int f = wn * 64 + ni * 16 + mxl;
        p2v[ni] = p2g[f];
        bv[ni] = bias[f];
    }
    const long obase = (long)bz * 112 * 112 * 128;
#pragma unroll
    for (int mi = 0; mi < 4; ++mi) {
        const int my = wm * 4 + mi;
        const int gy = y0 + my;
#pragma unroll
        for (int j = 0; j < 4; ++j) {
            const int mx = kq * 4 + j;
            const float inv = invxn[my * 16 + mx];
            const int gx = x0 + mx;
            float* op = out + obase + ((long)(gy * 112 + gx) << 7);
#pragma unroll
            for (int ni = 0; ni < 4; ++ni) {
                const float cosv = acc[mi][ni][j] * inv;
                const float av = fabsf(cosv) + EPS;
                const float r = fast_exp2(p2v[ni] * fast_log2(av));
                const float val = (cosv == 0.f) ? bv[ni] : (copysignf(r, cosv) + bv[ni]);
                op[wn * 64 + ni * 16 + mxl] = val;
            }
        }
    }
}

extern "C" void kernel_launch(void* const* d_in, const int* in_sizes, int n_in,
                              void* d_out, int out_size, void* d_ws, size_t ws_size,
                              hipStream_t stream) {
    const float* img = (const float*)d_in[0];
    const float* w   = (const float*)d_in[1];
    const float* b   = (const float*)d_in[2];
    const float* p   = (const float*)d_in[3];
    const float* q   = (const float*)d_in[4];
    float* out = (float*)d_out;

    short* Wn = (short*)d_ws;                          // 9*128*64 bf16 = 147456 B
    float* p2 = (float*)((char*)d_ws + 9 * 8192 * 2);  // 128 f32

    prep_kernel<<<9, 512, 0, stream>>>(w, p, Wn, p2);
    sharp_main<<<dim3(7, 7, 16), 512, 0, stream>>>(img, Wn, b, p2, q, out);
}

// Round 4
// 226.508 us; speedup vs baseline: 1.3227x; 1.1094x over previous
//
#include <hip/hip_runtime.h>
#include <hip/hip_bf16.h>

#define EPS 1e-7f

typedef __attribute__((ext_vector_type(8))) short short8;
typedef __attribute__((ext_vector_type(4))) float f32x4;

__device__ __forceinline__ short f2bf(float x) {
    __hip_bfloat16 h = __float2bfloat16(x);
    short r; __builtin_memcpy(&r, &h, 2); return r;
}

__device__ __forceinline__ float fast_log2(float x) {
    float r; asm("v_log_f32 %0, %1" : "=v"(r) : "v"(x)); return r;
}
__device__ __forceinline__ float fast_exp2(float x) {
    float r; asm("v_exp_f32 %0, %1" : "=v"(r) : "v"(x)); return r;
}

// ---------------- prep: w_norm + normalized bf16 W, layout [t][n=128][k=64] + p^2 ----------
__global__ void prep_kernel(const float* __restrict__ w, const float* __restrict__ p,
                            short* __restrict__ Wn, float* __restrict__ p2) {
    __shared__ float pn[4][128];
    __shared__ float sInv[128];
    const int t = blockIdx.x;        // tap 0..8
    const int tid = threadIdx.x;     // 0..511
    const int n = tid & 127, part = tid >> 7;
    float ssq = 0.f;
    const int k0 = part * 144;
    for (int k = k0; k < k0 + 144; ++k) {
        float v = w[k * 128 + n];
        ssq = fmaf(v, v, ssq);
    }
    pn[part][n] = ssq;
    __syncthreads();
    if (tid < 128) {
        float s = pn[0][tid] + pn[1][tid] + pn[2][tid] + pn[3][tid];
        sInv[tid] = 1.0f / sqrtf(fmaxf(s, EPS));
        if (t == 0) p2[tid] = p[tid] * p[tid];
    }
    __syncthreads();
    if (tid < 256) {
        const int nn = tid & 127, kh = tid >> 7;   // k-half
        const float inv = sInv[nn];
        short* dst = Wn + t * 8192 + nn * 64 + kh * 32;
        const float* src = w + (t * 64 + kh * 32) * 128 + nn;
#pragma unroll
        for (int j = 0; j < 32; ++j) dst[j] = f2bf(src[j * 128] * inv);
    }
}

// ---------------- main: implicit-GEMM 3x3 cosine conv ----------------
// tile: 16x16 pixels x 128 filters, 8 waves (4m x 2n), each wave 64 px x 64 filters
// MFMA operands: A = W (rows=filters), B = image (cols=pixel-x)  -> D rows = 4 consecutive
// filters per lane -> float4 output stores.
__global__ __launch_bounds__(512, 4)
void sharp_main(const float* __restrict__ img, const short* __restrict__ Wn,
                const float* __restrict__ bias, const float* __restrict__ p2g,
                const float* __restrict__ qp, float* __restrict__ out) {
    __shared__ __align__(16) unsigned char lds_img[41472];   // 324 pix * 64ch * 2B, swizzled
    __shared__ __align__(16) unsigned char lds_w[2][16384];  // per-tap [n=128][k=64] bf16, swizzled
    __shared__ float sArr[324];
    __shared__ float invxn[256];

    const int tid  = threadIdx.x;
    const int lane = tid & 63;
    const int wv   = tid >> 6;   // 0..7
    const int wm   = wv >> 1;    // 0..3 (m quadrant: 4 y-rows)
    const int wn   = wv & 1;     // 0..1 (n half: 64 filters)
    const int tx = blockIdx.x, ty = blockIdx.y, bz = blockIdx.z;
    const int y0 = ty * 16, x0 = tx * 16;

    const int mxl = lane & 15;   // fragment row/col index
    const int kq  = lane >> 4;   // k-quarter

    if (tid < 324) sArr[tid] = 0.f;
    __syncthreads();

    // ---- stage image tile (18x18 halo) f32 -> bf16 LDS, fused sum-of-squares ----
    {
        const long ibase = (long)bz * (112 * 112 * 64);
        for (int q = tid; q < 2592; q += 512) {   // 324 pixels * 8 chunks of 8ch
            const int pp = q >> 3, c8 = q & 7;
            const int py = pp / 18, px = pp % 18;
            const int gy = y0 - 1 + py, gx = x0 - 1 + px;
            short8 h = {0, 0, 0, 0, 0, 0, 0, 0};
            if ((unsigned)gy < 112u && (unsigned)gx < 112u) {
                const float* sp = img + ibase + ((gy * 112 + gx) << 6) + (c8 << 3);
                const float4 v0 = *reinterpret_cast<const float4*>(sp);
                const float4 v1 = *reinterpret_cast<const float4*>(sp + 4);
                float ss = v0.x * v0.x + v0.y * v0.y + v0.z * v0.z + v0.w * v0.w
                         + v1.x * v1.x + v1.y * v1.y + v1.z * v1.z + v1.w * v1.w;
                h[0] = f2bf(v0.x); h[1] = f2bf(v0.y); h[2] = f2bf(v0.z); h[3] = f2bf(v0.w);
                h[4] = f2bf(v1.x); h[5] = f2bf(v1.y); h[6] = f2bf(v1.z); h[7] = f2bf(v1.w);
                atomicAdd(&sArr[pp], ss);
            }
            const int addr = (pp << 7) + (((c8 << 4)) ^ ((pp & 7) << 4));
            *reinterpret_cast<short8*>(lds_img + addr) = h;
        }
    }

    // ---- stage W tap0 into lds_w[0]; prefetch tap1 into regs ----
    const uint4* wg = reinterpret_cast<const uint4*>(Wn);  // 1024 uint4 per tap
    const int wi0 = tid * 2, wi1 = tid * 2 + 1;
    const int wa0 = (tid * 32) ^ ((((tid * 32) >> 7) & 7) << 4);
    const int wa1 = (tid * 32 + 16) ^ ((((tid * 32) >> 7) & 7) << 4);
    uint4 r0 = wg[wi0], r1 = wg[wi1];
    *reinterpret_cast<uint4*>(lds_w[0] + wa0) = r0;
    *reinterpret_cast<uint4*>(lds_w[0] + wa1) = r1;
    r0 = wg[1024 + wi0]; r1 = wg[1024 + wi1];   // tap1 in regs

    __syncthreads();

    // ---- per-pixel inverse norm from 3x3 box of channel sumsq ----
    if (tid < 256) {
        const int my = tid >> 4, mx = tid & 15;
        float s9 = 0.f;
#pragma unroll
        for (int dy = 0; dy < 3; ++dy)
#pragma unroll
            for (int dx = 0; dx < 3; ++dx)
                s9 += sArr[(my + dy) * 18 + (mx + dx)];
        const float qv = qp[0];
        invxn[tid] = 1.0f / (sqrtf(fmaxf(s9, EPS)) + qv * qv);
    }
    __syncthreads();

    // ---- main MFMA loop: 9 taps x 2 k-steps, W double-buffered in LDS ----
    f32x4 acc[4][4];
#pragma unroll
    for (int mi = 0; mi < 4; ++mi)
#pragma unroll
        for (int ni = 0; ni < 4; ++ni)
            acc[mi][ni] = (f32x4){0.f, 0.f, 0.f, 0.f};

#pragma unroll
    for (int t = 0; t < 9; ++t) {
        const int dy = t / 3, dx = t % 3;
        if (t < 8) {
            // write prefetched tap t+1 into the other buffer (last read of it was tap t-1)
            *reinterpret_cast<uint4*>(lds_w[(t + 1) & 1] + wa0) = r0;
            *reinterpret_cast<uint4*>(lds_w[(t + 1) & 1] + wa1) = r1;
            if (t < 7) { r0 = wg[(t + 2) * 1024 + wi0]; r1 = wg[(t + 2) * 1024 + wi1]; }
        }
#pragma unroll
        for (int ks = 0; ks < 2; ++ks) {
            short8 wf[4], af[4];
#pragma unroll
            for (int ni = 0; ni < 4; ++ni) {
                const int nn = wn * 64 + ni * 16 + mxl;
                const int addr = (nn << 7) + ((ks * 64 + kq * 16) ^ ((nn & 7) << 4));
                wf[ni] = *reinterpret_cast<const short8*>(lds_w[t & 1] + addr);
            }
#pragma unroll
            for (int mi = 0; mi < 4; ++mi) {
                const int pp = (wm * 4 + mi + dy) * 18 + mxl + dx;
                const int addr = (pp << 7) + ((ks * 64 + kq * 16) ^ ((pp & 7) << 4));
                af[mi] = *reinterpret_cast<const short8*>(lds_img + addr);
            }
#pragma unroll
            for (int mi = 0; mi < 4; ++mi)
#pragma unroll
                for (int ni = 0; ni < 4; ++ni)
                    acc[mi][ni] = __builtin_amdgcn_mfma_f32_16x16x32_bf16(
                        wf[ni], af[mi], acc[mi][ni], 0, 0, 0);
        }
        __syncthreads();
    }

    // ---- epilogue: cosine, sharpen (hw exp2/log2), bias, float4 store ----
    f32x4 p2v[4], bv[4];
#pragma unroll
    for (int ni = 0; ni < 4; ++ni) {
        const int f0 = wn * 64 + ni * 16 + kq * 4;
        p2v[ni] = *reinterpret_cast<const f32x4*>(p2g + f0);
        bv[ni]  = *reinterpret_cast<const f32x4*>(bias + f0);
    }
    const long obase = (long)bz * 112 * 112 * 128;
#pragma unroll
    for (int mi = 0; mi < 4; ++mi) {
        const int my = wm * 4 + mi;
        const int gy = y0 + my;
        const float inv = invxn[my * 16 + mxl];
        float* op = out + obase + ((long)(gy * 112 + x0 + mxl) << 7);
#pragma unroll
        for (int ni = 0; ni < 4; ++ni) {
            f32x4 v;
#pragma unroll
            for (int j = 0; j < 4; ++j) {
                const float cosv = acc[mi][ni][j] * inv;
                const float av = fabsf(cosv) + EPS;
                const float r = fast_exp2(p2v[ni][j] * fast_log2(av));
                v[j] = (cosv == 0.f) ? bv[ni][j] : (copysignf(r, cosv) + bv[ni][j]);
            }
            *reinterpret_cast<f32x4*>(op + wn * 64 + ni * 16 + kq * 4) = v;
        }
    }
}

extern "C" void kernel_launch(void* const* d_in, const int* in_sizes, int n_in,
                              void* d_out, int out_size, void* d_ws, size_t ws_size,
                              hipStream_t stream) {
    const float* img = (const float*)d_in[0];
    const float* w   = (const float*)d_in[1];
    const float* b   = (const float*)d_in[2];
    const float* p   = (const float*)d_in[3];
    const float* q   = (const float*)d_in[4];
    float* out = (float*)d_out;

    short* Wn = (short*)d_ws;                          // 9*128*64 bf16 = 147456 B
    float* p2 = (float*)((char*)d_ws + 9 * 8192 * 2);  // 128 f32

    prep_kernel<<<9, 512, 0, stream>>>(w, p, Wn, p2);
    sharp_main<<<dim3(7, 7, 16), 512, 0, stream>>>(img, Wn, b, p2, q, out);
}

// Round 5
// 218.651 us; speedup vs baseline: 1.3702x; 1.0359x over previous
//
#include <hip/hip_runtime.h>
#include <hip/hip_bf16.h>

#define EPS 1e-7f

typedef __attribute__((ext_vector_type(8))) short short8;
typedef __attribute__((ext_vector_type(4))) float f32x4;

__device__ __forceinline__ short f2bf(float x) {
    __hip_bfloat16 h = __float2bfloat16(x);
    short r; __builtin_memcpy(&r, &h, 2); return r;
}

__device__ __forceinline__ float fast_log2(float x) {
    float r; asm("v_log_f32 %0, %1" : "=v"(r) : "v"(x)); return r;
}
__device__ __forceinline__ float fast_exp2(float x) {
    float r; asm("v_exp_f32 %0, %1" : "=v"(r) : "v"(x)); return r;
}

// ---------------- prep: w_norm + normalized bf16 W, layout [t][n=128][k=64] + p^2 ----------
__global__ void prep_kernel(const float* __restrict__ w, const float* __restrict__ p,
                            short* __restrict__ Wn, float* __restrict__ p2) {
    __shared__ float pn[4][128];
    __shared__ float sInv[128];
    const int t = blockIdx.x;        // tap 0..8
    const int tid = threadIdx.x;     // 0..511
    const int n = tid & 127, part = tid >> 7;
    float ssq = 0.f;
    const int k0 = part * 144;
    for (int k = k0; k < k0 + 144; ++k) {
        float v = w[k * 128 + n];
        ssq = fmaf(v, v, ssq);
    }
    pn[part][n] = ssq;
    __syncthreads();
    if (tid < 128) {
        float s = pn[0][tid] + pn[1][tid] + pn[2][tid] + pn[3][tid];
        sInv[tid] = 1.0f / sqrtf(fmaxf(s, EPS));
        if (t == 0) p2[tid] = p[tid] * p[tid];
    }
    __syncthreads();
    if (tid < 256) {
        const int nn = tid & 127, kh = tid >> 7;   // k-half
        const float inv = sInv[nn];
        short* dst = Wn + t * 8192 + nn * 64 + kh * 32;
        const float* src = w + (t * 64 + kh * 32) * 128 + nn;
#pragma unroll
        for (int j = 0; j < 32; ++j) dst[j] = f2bf(src[j * 128] * inv);
    }
}

// ---------------- main: implicit-GEMM 3x3 cosine conv ----------------
// tile: 16x16 pixels x 128 filters, 8 waves (4m x 2n), each wave 64 px x 64 filters
// A = W (rows=filters), B = image (cols=pixel-x). Epilogue transposes per-wave
// through LDS so each global store writes 4 pixels x 256B contiguous.
__global__ __launch_bounds__(512, 4)
void sharp_main(const float* __restrict__ img, const short* __restrict__ Wn,
                const float* __restrict__ bias, const float* __restrict__ p2g,
                const float* __restrict__ qp, float* __restrict__ out) {
    __shared__ __align__(16) unsigned char lds_img[41472];   // 324 pix * 64ch * 2B, swizzled
    __shared__ __align__(16) unsigned char lds_w[2][16384];  // per-tap [n=128][k=64] bf16, swizzled
    __shared__ float sArr[324];
    __shared__ float invxn[256];

    const int tid  = threadIdx.x;
    const int lane = tid & 63;
    const int wv   = tid >> 6;   // 0..7
    const int wm   = wv >> 1;    // 0..3 (m quadrant: 4 y-rows)
    const int wn   = wv & 1;     // 0..1 (n half: 64 filters)

    // bijective XCD swizzle: 784 = 8*98; each XCD gets 98 consecutive tiles (= 2 images)
    const int bid  = blockIdx.x;
    const int work = (bid & 7) * 98 + (bid >> 3);
    const int bz = work / 49;
    const int rem = work - bz * 49;
    const int ty = rem / 7, tx = rem - ty * 7;
    const int y0 = ty * 16, x0 = tx * 16;

    const int mxl = lane & 15;   // fragment col index (pixel-x / filter-within-16's pair)
    const int kq  = lane >> 4;   // k-quarter

    // ---- stage image tile (18x18 halo) f32 -> bf16 LDS, fused sum-of-squares ----
    {
        const long ibase = (long)bz * (112 * 112 * 64);
        for (int q = tid; q < 2592; q += 512) {   // 324 pixels * 8 chunks of 8ch
            const int pp = q >> 3, c8 = q & 7;
            const int py = pp / 18, px = pp % 18;
            const int gy = y0 - 1 + py, gx = x0 - 1 + px;
            short8 h = {0, 0, 0, 0, 0, 0, 0, 0};
            float ss = 0.f;
            if ((unsigned)gy < 112u && (unsigned)gx < 112u) {
                const float* sp = img + ibase + ((gy * 112 + gx) << 6) + (c8 << 3);
                const float4 v0 = *reinterpret_cast<const float4*>(sp);
                const float4 v1 = *reinterpret_cast<const float4*>(sp + 4);
                ss = v0.x * v0.x + v0.y * v0.y + v0.z * v0.z + v0.w * v0.w
                   + v1.x * v1.x + v1.y * v1.y + v1.z * v1.z + v1.w * v1.w;
                h[0] = f2bf(v0.x); h[1] = f2bf(v0.y); h[2] = f2bf(v0.z); h[3] = f2bf(v0.w);
                h[4] = f2bf(v1.x); h[5] = f2bf(v1.y); h[6] = f2bf(v1.z); h[7] = f2bf(v1.w);
            }
            // 8-lane group reduce (lanes q: same pp, c8=0..7) -> one plain write per pixel
            ss += __shfl_xor(ss, 1);
            ss += __shfl_xor(ss, 2);
            ss += __shfl_xor(ss, 4);
            if ((q & 7) == 0) sArr[pp] = ss;
            const int addr = (pp << 7) + (((c8 << 4)) ^ ((pp & 7) << 4));
            *reinterpret_cast<short8*>(lds_img + addr) = h;
        }
    }

    // ---- stage W tap0 into lds_w[0]; prefetch tap1 into regs ----
    const uint4* wg = reinterpret_cast<const uint4*>(Wn);  // 1024 uint4 per tap
    const int wi0 = tid * 2, wi1 = tid * 2 + 1;
    const int wa0 = (tid * 32) ^ ((((tid * 32) >> 7) & 7) << 4);
    const int wa1 = (tid * 32 + 16) ^ ((((tid * 32) >> 7) & 7) << 4);
    uint4 r0 = wg[wi0], r1 = wg[wi1];
    *reinterpret_cast<uint4*>(lds_w[0] + wa0) = r0;
    *reinterpret_cast<uint4*>(lds_w[0] + wa1) = r1;
    r0 = wg[1024 + wi0]; r1 = wg[1024 + wi1];   // tap1 in regs

    __syncthreads();

    // ---- per-pixel inverse norm from 3x3 box of channel sumsq ----
    if (tid < 256) {
        const int my = tid >> 4, mx = tid & 15;
        float s9 = 0.f;
#pragma unroll
        for (int dy = 0; dy < 3; ++dy)
#pragma unroll
            for (int dx = 0; dx < 3; ++dx)
                s9 += sArr[(my + dy) * 18 + (mx + dx)];
        const float qv = qp[0];
        invxn[tid] = 1.0f / (sqrtf(fmaxf(s9, EPS)) + qv * qv);
    }
    __syncthreads();

    // ---- main MFMA loop: 9 taps x 2 k-steps, W double-buffered in LDS ----
    f32x4 acc[4][4];
#pragma unroll
    for (int mi = 0; mi < 4; ++mi)
#pragma unroll
        for (int ni = 0; ni < 4; ++ni)
            acc[mi][ni] = (f32x4){0.f, 0.f, 0.f, 0.f};

#pragma unroll
    for (int t = 0; t < 9; ++t) {
        const int dy = t / 3, dx = t % 3;
        if (t < 8) {
            *reinterpret_cast<uint4*>(lds_w[(t + 1) & 1] + wa0) = r0;
            *reinterpret_cast<uint4*>(lds_w[(t + 1) & 1] + wa1) = r1;
            if (t < 7) { r0 = wg[(t + 2) * 1024 + wi0]; r1 = wg[(t + 2) * 1024 + wi1]; }
        }
#pragma unroll
        for (int ks = 0; ks < 2; ++ks) {
            short8 wf[4], af[4];
#pragma unroll
            for (int ni = 0; ni < 4; ++ni) {
                const int nn = wn * 64 + ni * 16 + mxl;
                const int addr = (nn << 7) + ((ks * 64 + kq * 16) ^ ((nn & 7) << 4));
                wf[ni] = *reinterpret_cast<const short8*>(lds_w[t & 1] + addr);
            }
#pragma unroll
            for (int mi = 0; mi < 4; ++mi) {
                const int pp = (wm * 4 + mi + dy) * 18 + mxl + dx;
                const int addr = (pp << 7) + ((ks * 64 + kq * 16) ^ ((pp & 7) << 4));
                af[mi] = *reinterpret_cast<const short8*>(lds_img + addr);
            }
#pragma unroll
            for (int mi = 0; mi < 4; ++mi)
#pragma unroll
                for (int ni = 0; ni < 4; ++ni)
                    acc[mi][ni] = __builtin_amdgcn_mfma_f32_16x16x32_bf16(
                        wf[ni], af[mi], acc[mi][ni], 0, 0, 0);
        }
        __syncthreads();   // final iteration's barrier also guards scratch reuse below
    }

    // ---- epilogue: sharpen, per-wave LDS transpose, contiguous 256B/pixel stores ----
    f32x4 p2v[4], bv[4];
#pragma unroll
    for (int ni = 0; ni < 4; ++ni) {
        const int f0 = wn * 64 + ni * 16 + kq * 4;
        p2v[ni] = *reinterpret_cast<const f32x4*>(p2g + f0);
        bv[ni]  = *reinterpret_cast<const f32x4*>(bias + f0);
    }
    const long obase = (long)bz * 112 * 112 * 128;
    unsigned char* scratch = lds_img + (wv << 12);   // 4KB private per wave
#pragma unroll
    for (int mi = 0; mi < 4; ++mi) {
        const int my = wm * 4 + mi;
        const int gy = y0 + my;
        const float inv = invxn[my * 16 + mxl];
        // scatter: value for (pixel=mxl, filter=ni*16+kq*4+j) -> scratch[mxl][f]
#pragma unroll
        for (int ni = 0; ni < 4; ++ni) {
            f32x4 v;
#pragma unroll
            for (int j = 0; j < 4; ++j) {
                const float cosv = acc[mi][ni][j] * inv;
                const float av = fabsf(cosv) + EPS;
                const float r = fast_exp2(p2v[ni][j] * fast_log2(av));
                v[j] = (cosv == 0.f) ? bv[ni][j] : (copysignf(r, cosv) + bv[ni][j]);
            }
            const int wb = (mxl * 256 + ni * 64 + kq * 16) ^ ((mxl & 7) << 4);
            *reinterpret_cast<f32x4*>(scratch + wb) = v;
        }
        // gather: lane reads (pixel p = it*4+kq, filters mxl*4..mxl*4+3) -> 256B/pixel stores
#pragma unroll
        for (int it = 0; it < 4; ++it) {
            const int p = it * 4 + kq;
            const int rb = (p * 256 + mxl * 16) ^ ((p & 7) << 4);
            const f32x4 v = *reinterpret_cast<const f32x4*>(scratch + rb);
            float* op = out + obase + ((long)(gy * 112 + x0 + p) << 7) + wn * 64 + mxl * 4;
            *reinterpret_cast<f32x4*>(op) = v;
        }
    }
}

extern "C" void kernel_launch(void* const* d_in, const int* in_sizes, int n_in,
                              void* d_out, int out_size, void* d_ws, size_t ws_size,
                              hipStream_t stream) {
    const float* img = (const float*)d_in[0];
    const float* w   = (const float*)d_in[1];
    const float* b   = (const float*)d_in[2];
    const float* p   = (const float*)d_in[3];
    const float* q   = (const float*)d_in[4];
    float* out = (float*)d_out;

    short* Wn = (short*)d_ws;                          // 9*128*64 bf16 = 147456 B
    float* p2 = (float*)((char*)d_ws + 9 * 8192 * 2);  // 128 f32

    prep_kernel<<<9, 512, 0, stream>>>(w, p, Wn, p2);
    sharp_main<<<784, 512, 0, stream>>>(img, Wn, b, p2, q, out);
}